// Round 3
// baseline (95.894 us; speedup 1.0000x reference)
//
#include <hip/hip_runtime.h>
#include <math.h>

#define NPTS 1024
#define CH 256
#define CW 256

// -------- prep: fold all per-point constants into a packed table in d_ws ----
// A[n] = (t00, t10, b0, t01)   where tij = 0.5 * (matrix_offsets + s*I)[i][j]
// B[n] = (t11, b1, ca0, ca1)   b_j = -(ly*t0j + lx*t1j),  ca_c = color_c*alpha
// C[n] = ca2
__global__ __launch_bounds__(256) void prep_kernel(
    const float* __restrict__ loc,   // (N,2)  [y, x]
    const float* __restrict__ mo,    // (N,2,2)
    const float* __restrict__ mso,   // (N,)
    const float* __restrict__ col,   // (N,3)
    const float* __restrict__ alp,   // (N,)
    float4* __restrict__ A,
    float4* __restrict__ B,
    float*  __restrict__ C)
{
    int n = blockIdx.x * blockDim.x + threadIdx.x;
    if (n >= NPTS) return;
    float s   = 16.0f * __expf(mso[n]);   // sqrt(1024)/2 * exp(offset)
    float t00 = 0.5f * (mo[4*n+0] + s);
    float t01 = 0.5f * (mo[4*n+1]);
    float t10 = 0.5f * (mo[4*n+2]);
    float t11 = 0.5f * (mo[4*n+3] + s);
    float ly  = loc[2*n+0];
    float lx  = loc[2*n+1];
    float b0  = -(ly*t00 + lx*t10);
    float b1  = -(ly*t01 + lx*t11);
    float a   = alp[n];
    A[n] = make_float4(t00, t10, b0, t01);
    B[n] = make_float4(t11, b1, col[3*n+0]*a, col[3*n+1]*a);
    C[n] = col[3*n+2]*a;
}

// -------- render: 1 pixel per thread, loop over all points ------------------
__global__ __launch_bounds__(256) void render_kernel(
    const float4* __restrict__ A,
    const float4* __restrict__ B,
    const float*  __restrict__ C,
    float* __restrict__ out)
{
    int tid = blockIdx.x * 256 + threadIdx.x;
    int h = tid >> 8;          // W == 256
    int w = tid & 255;
    float y = fmaf((float)h, 2.0f/255.0f, -1.0f);
    float x = fmaf((float)w, 2.0f/255.0f, -1.0f);

    float acc0 = 0.0f, acc1 = 0.0f, acc2 = 0.0f;

    #pragma unroll 8
    for (int n = 0; n < NPTS; ++n) {
        float4 a = A[n];   // uniform index -> scalar loads expected
        float4 b = B[n];
        float  c = C[n];
        float t0 = fmaf(y, a.x, fmaf(x, a.y, a.z));
        float t1 = fmaf(y, a.w, fmaf(x, b.x, b.y));
        float m  = 1.0f - (fabsf(t0) + fabsf(t1));
        m = fmaxf(m, 0.0f);
        acc0 = fmaf(b.z, m, acc0);
        acc1 = fmaf(b.w, m, acc1);
        acc2 = fmaf(c,   m, acc2);
    }

    int o = tid * 3;
    out[o+0] = 1.0f / (1.0f + __expf(-4.0f * acc0));
    out[o+1] = 1.0f / (1.0f + __expf(-4.0f * acc1));
    out[o+2] = 1.0f / (1.0f + __expf(-4.0f * acc2));
}

extern "C" void kernel_launch(void* const* d_in, const int* in_sizes, int n_in,
                              void* d_out, int out_size, void* d_ws, size_t ws_size,
                              hipStream_t stream) {
    const float* loc = (const float*)d_in[0];   // locations      (1,1,N,2)
    const float* mo  = (const float*)d_in[1];   // matrix_offsets (N,2,2)
    const float* mso = (const float*)d_in[2];   // scale offsets  (N,1,1)
    const float* col = (const float*)d_in[3];   // colors         (1,1,N,3)
    const float* alp = (const float*)d_in[4];   // alphas         (1,1,N,1)
    float* out = (float*)d_out;

    float4* A = (float4*)d_ws;                  // 16 KB
    float4* B = A + NPTS;                       // 16 KB
    float*  C = (float*)(B + NPTS);             // 4 KB

    prep_kernel<<<(NPTS + 255) / 256, 256, 0, stream>>>(loc, mo, mso, col, alp, A, B, C);

    int pixels = CH * CW;
    render_kernel<<<pixels / 256, 256, 0, stream>>>(A, B, C, out);
}

// Round 4
// 34.853 us; speedup vs baseline: 2.7514x; 2.7514x over previous
//
#include <hip/hip_runtime.h>
#include <math.h>

#define NPTS 1024
#define CH 256
#define CW 256
#define PIX (CH*CW)
#define NELEM (PIX*3)

// -------- prep: fold all per-point constants into a packed table ------------
// A[n] = (t00, t10, b0, t01)   tij = 0.5*(matrix_offsets + s*I)[i][j]
// B[n] = (t11, b1, ca0, ca1)   b_j = -(ly*t0j + lx*t1j),  ca_c = color_c*alpha
// C[n] = ca2
__global__ __launch_bounds__(256) void prep_kernel(
    const float* __restrict__ loc, const float* __restrict__ mo,
    const float* __restrict__ mso, const float* __restrict__ col,
    const float* __restrict__ alp,
    float4* __restrict__ A, float4* __restrict__ B, float* __restrict__ C)
{
    int n = blockIdx.x * blockDim.x + threadIdx.x;
    if (n >= NPTS) return;
    float s   = 16.0f * __expf(mso[n]);
    float t00 = 0.5f * (mo[4*n+0] + s);
    float t01 = 0.5f * (mo[4*n+1]);
    float t10 = 0.5f * (mo[4*n+2]);
    float t11 = 0.5f * (mo[4*n+3] + s);
    float ly  = loc[2*n+0];
    float lx  = loc[2*n+1];
    float b0  = -(ly*t00 + lx*t10);
    float b1  = -(ly*t01 + lx*t11);
    float a   = alp[n];
    A[n] = make_float4(t00, t10, b0, t01);
    B[n] = make_float4(t11, b1, col[3*n+0]*a, col[3*n+1]*a);
    C[n] = col[3*n+2]*a;
}

// -------- render: 4 pixels/thread (same column, 4 rows), K-split over points
// grid = 64 tiles * ksplit.  tile = blockIdx.x % 64, seg = blockIdx.x / 64.
// Writes partial sums (no sigmoid) to part + seg*NELEM.
__global__ __launch_bounds__(256) void render_part_kernel(
    const float4* __restrict__ A, const float4* __restrict__ B,
    const float*  __restrict__ C, float* __restrict__ part,
    int ksplit, int ppb)
{
    int tile = blockIdx.x & 63;
    int seg  = blockIdx.x >> 6;
    int w    = threadIdx.x;
    int r0   = tile * 4;
    float x  = fmaf((float)w, 2.0f/255.0f, -1.0f);
    float y0 = fmaf((float)r0, 2.0f/255.0f, -1.0f);
    const float dy = 2.0f/255.0f;
    float y1 = y0 + dy, y2 = y1 + dy, y3 = y2 + dy;

    float ac00=0,ac01=0,ac02=0, ac10=0,ac11=0,ac12=0;
    float ac20=0,ac21=0,ac22=0, ac30=0,ac31=0,ac32=0;

    int n0 = seg * ppb, n1 = n0 + ppb;
    #pragma unroll 4
    for (int n = n0; n < n1; ++n) {
        float4 a = A[n];
        float4 b = B[n];
        float  c = C[n];
        float u0 = fmaf(x, a.y, a.z);   // x*t10 + b0
        float u1 = fmaf(x, b.x, b.y);   // x*t11 + b1
        {
            float t0 = fmaf(y0, a.x, u0), t1 = fmaf(y0, a.w, u1);
            float m = fmaxf(1.0f - (fabsf(t0) + fabsf(t1)), 0.0f);
            ac00 = fmaf(b.z, m, ac00); ac01 = fmaf(b.w, m, ac01); ac02 = fmaf(c, m, ac02);
        }
        {
            float t0 = fmaf(y1, a.x, u0), t1 = fmaf(y1, a.w, u1);
            float m = fmaxf(1.0f - (fabsf(t0) + fabsf(t1)), 0.0f);
            ac10 = fmaf(b.z, m, ac10); ac11 = fmaf(b.w, m, ac11); ac12 = fmaf(c, m, ac12);
        }
        {
            float t0 = fmaf(y2, a.x, u0), t1 = fmaf(y2, a.w, u1);
            float m = fmaxf(1.0f - (fabsf(t0) + fabsf(t1)), 0.0f);
            ac20 = fmaf(b.z, m, ac20); ac21 = fmaf(b.w, m, ac21); ac22 = fmaf(c, m, ac22);
        }
        {
            float t0 = fmaf(y3, a.x, u0), t1 = fmaf(y3, a.w, u1);
            float m = fmaxf(1.0f - (fabsf(t0) + fabsf(t1)), 0.0f);
            ac30 = fmaf(b.z, m, ac30); ac31 = fmaf(b.w, m, ac31); ac32 = fmaf(c, m, ac32);
        }
    }

    float* p = part + (size_t)seg * NELEM;
    int i0 = (r0 * 256 + w) * 3;
    p[i0+0]=ac00;        p[i0+1]=ac01;        p[i0+2]=ac02;
    p[i0+768+0]=ac10;    p[i0+768+1]=ac11;    p[i0+768+2]=ac12;
    p[i0+1536+0]=ac20;   p[i0+1536+1]=ac21;   p[i0+1536+2]=ac22;
    p[i0+2304+0]=ac30;   p[i0+2304+1]=ac31;   p[i0+2304+2]=ac32;
}

// -------- reduce partials + sigmoid -----------------------------------------
__global__ __launch_bounds__(256) void reduce_kernel(
    const float* __restrict__ part, float* __restrict__ out, int ksplit)
{
    int i = blockIdx.x * 256 + threadIdx.x;
    if (i >= NELEM) return;
    float s = 0.0f;
    for (int k = 0; k < ksplit; ++k) s += part[(size_t)k * NELEM + i];
    out[i] = 1.0f / (1.0f + __expf(-4.0f * s));
}

// -------- fallback: direct render (no split) if ws too small ----------------
__global__ __launch_bounds__(256) void render_direct_kernel(
    const float4* __restrict__ A, const float4* __restrict__ B,
    const float*  __restrict__ C, float* __restrict__ out)
{
    int tile = blockIdx.x;
    int w    = threadIdx.x;
    int r0   = tile * 4;
    float x  = fmaf((float)w, 2.0f/255.0f, -1.0f);
    float y0 = fmaf((float)r0, 2.0f/255.0f, -1.0f);
    const float dy = 2.0f/255.0f;
    float ys[4] = {y0, y0+dy, y0+2*dy, y0+3*dy};
    float ac[4][3] = {};
    #pragma unroll 4
    for (int n = 0; n < NPTS; ++n) {
        float4 a = A[n]; float4 b = B[n]; float c = C[n];
        float u0 = fmaf(x, a.y, a.z);
        float u1 = fmaf(x, b.x, b.y);
        #pragma unroll
        for (int j = 0; j < 4; ++j) {
            float t0 = fmaf(ys[j], a.x, u0), t1 = fmaf(ys[j], a.w, u1);
            float m = fmaxf(1.0f - (fabsf(t0) + fabsf(t1)), 0.0f);
            ac[j][0] = fmaf(b.z, m, ac[j][0]);
            ac[j][1] = fmaf(b.w, m, ac[j][1]);
            ac[j][2] = fmaf(c,   m, ac[j][2]);
        }
    }
    #pragma unroll
    for (int j = 0; j < 4; ++j) {
        int i = ((r0 + j) * 256 + w) * 3;
        out[i+0] = 1.0f / (1.0f + __expf(-4.0f * ac[j][0]));
        out[i+1] = 1.0f / (1.0f + __expf(-4.0f * ac[j][1]));
        out[i+2] = 1.0f / (1.0f + __expf(-4.0f * ac[j][2]));
    }
}

extern "C" void kernel_launch(void* const* d_in, const int* in_sizes, int n_in,
                              void* d_out, int out_size, void* d_ws, size_t ws_size,
                              hipStream_t stream) {
    const float* loc = (const float*)d_in[0];
    const float* mo  = (const float*)d_in[1];
    const float* mso = (const float*)d_in[2];
    const float* col = (const float*)d_in[3];
    const float* alp = (const float*)d_in[4];
    float* out = (float*)d_out;

    const size_t SLICE = (size_t)NELEM * sizeof(float);          // 768 KB
    const size_t TBL   = (2*sizeof(float4) + sizeof(float)) * NPTS; // 36 KB

    int ksplit = 16;
    while (ksplit > 1 && (size_t)ksplit * SLICE + TBL > ws_size) ksplit >>= 1;

    if (SLICE + TBL <= ws_size) {
        float* part = (float*)d_ws;
        float4* A = (float4*)((char*)d_ws + (size_t)ksplit * SLICE);
        float4* B = A + NPTS;
        float*  C = (float*)(B + NPTS);
        prep_kernel<<<(NPTS+255)/256, 256, 0, stream>>>(loc, mo, mso, col, alp, A, B, C);
        render_part_kernel<<<64 * ksplit, 256, 0, stream>>>(A, B, C, part, ksplit, NPTS / ksplit);
        reduce_kernel<<<(NELEM+255)/256, 256, 0, stream>>>(part, out, ksplit);
    } else {
        float4* A = (float4*)d_ws;
        float4* B = A + NPTS;
        float*  C = (float*)(B + NPTS);
        prep_kernel<<<(NPTS+255)/256, 256, 0, stream>>>(loc, mo, mso, col, alp, A, B, C);
        render_direct_kernel<<<64, 256, 0, stream>>>(A, B, C, out);
    }
}

// Round 5
// 16.072 us; speedup vs baseline: 5.9663x; 2.1685x over previous
//
#include <hip/hip_runtime.h>
#include <math.h>

#define NPTS 1024
#define CH 256
#define CW 256

// -------- prep: fold all per-point constants into a packed table ------------
// A[n] = (t00, t10, b0, t01)   tij = 0.5*(matrix_offsets + s*I)[i][j]
// B[n] = (t11, b1, ca0, ca1)   b_j = -(ly*t0j + lx*t1j),  ca_c = color_c*alpha
// C[n] = ca2
// Row NPTS is a zero sentinel (contributes 0 regardless of m) used to pad
// the per-wave survivor list to a multiple of 4.
__global__ __launch_bounds__(256) void prep_kernel(
    const float* __restrict__ loc, const float* __restrict__ mo,
    const float* __restrict__ mso, const float* __restrict__ col,
    const float* __restrict__ alp,
    float4* __restrict__ A, float4* __restrict__ B, float* __restrict__ C)
{
    int n = blockIdx.x * blockDim.x + threadIdx.x;
    if (n >= NPTS) return;
    float s   = 16.0f * __expf(mso[n]);
    float t00 = 0.5f * (mo[4*n+0] + s);
    float t01 = 0.5f * (mo[4*n+1]);
    float t10 = 0.5f * (mo[4*n+2]);
    float t11 = 0.5f * (mo[4*n+3] + s);
    float ly  = loc[2*n+0];
    float lx  = loc[2*n+1];
    float b0  = -(ly*t00 + lx*t10);
    float b1  = -(ly*t01 + lx*t11);
    float a   = alp[n];
    A[n] = make_float4(t00, t10, b0, t01);
    B[n] = make_float4(t11, b1, col[3*n+0]*a, col[3*n+1]*a);
    C[n] = col[3*n+2]*a;
    if (n == 0) {
        A[NPTS] = make_float4(0.f, 0.f, 0.f, 0.f);
        B[NPTS] = make_float4(0.f, 0.f, 0.f, 0.f);
        C[NPTS] = 0.f;
    }
}

// -------- render: 1024 blocks, 64 px/block (one row chunk), 4-way in-block
// point split (one 256-pt segment per wave), conservative cull + ballot
// compaction, LDS reduce + sigmoid. --------------------------------------
__global__ __launch_bounds__(256) void render_kernel(
    const float4* __restrict__ A, const float4* __restrict__ B,
    const float*  __restrict__ C, float* __restrict__ out)
{
    __shared__ int   list[4][256];
    __shared__ float part[4][64][3];

    int lane = threadIdx.x & 63;
    int seg  = threadIdx.x >> 6;
    int h    = blockIdx.x >> 2;           // 64 px = quarter of a 256-px row
    int w0   = (blockIdx.x & 3) << 6;

    float y  = fmaf((float)h,           2.0f/255.0f, -1.0f);
    float x  = fmaf((float)(w0 + lane), 2.0f/255.0f, -1.0f);
    float x0 = fmaf((float)w0,          2.0f/255.0f, -1.0f);
    float x1 = fmaf((float)(w0 + 63),   2.0f/255.0f, -1.0f);

    // ---- phase 1: test this wave's 256 points against the pixel interval.
    // t0(x) = x*t10 + (y*t00 + b0), t1(x) = x*t11 + (y*t01 + b1) are linear
    // in x at fixed y. Exact interval min of |t0|: 0 if sign change, else
    // min of endpoint magnitudes. Skip iff min|t0| + min|t1| >= 1 (=> m<=0
    // for every pixel in the tile). Conservative => identical output.
    int segbase = seg << 8;
    unsigned long long lt = (1ull << lane) - 1ull;
    int base = 0;
    #pragma unroll
    for (int j = 0; j < 4; ++j) {
        int idx = segbase + (j << 6) + lane;     // coalesced per round
        float4 a = A[idx];
        float4 b = B[idx];
        float c0 = fmaf(y, a.x, a.z);
        float c1 = fmaf(y, a.w, b.y);
        float g00 = fmaf(x0, a.y, c0), g01 = fmaf(x1, a.y, c0);
        float g10 = fmaf(x0, b.x, c1), g11 = fmaf(x1, b.x, c1);
        float m0 = (g00 * g01 <= 0.0f) ? 0.0f : fminf(fabsf(g00), fabsf(g01));
        float m1 = (g10 * g11 <= 0.0f) ? 0.0f : fminf(fabsf(g10), fabsf(g11));
        bool keep = (m0 + m1) < 1.0f;
        unsigned long long mk = __ballot(keep);
        if (keep) list[seg][base + __popcll(mk & lt)] = idx;
        base += __popcll(mk);
    }
    int cnt  = base;
    int cntp = (cnt + 3) & ~3;
    if (lane < cntp - cnt) list[seg][cnt + lane] = NPTS;   // sentinel pad

    // ---- phase 2: evaluate survivors (scalar table loads via readfirstlane)
    float ac0 = 0.f, ac1 = 0.f, ac2 = 0.f;
    for (int i = 0; i < cntp; i += 4) {
        int4 iv = *(const int4*)&list[seg][i];   // wave-uniform LDS read
        #pragma unroll
        for (int j = 0; j < 4; ++j) {
            int idv = (j == 0) ? iv.x : (j == 1) ? iv.y : (j == 2) ? iv.z : iv.w;
            int idx = __builtin_amdgcn_readfirstlane(idv);
            float4 a = A[idx];
            float4 b = B[idx];
            float  c = C[idx];
            float t0 = fmaf(x, a.y, fmaf(y, a.x, a.z));
            float t1 = fmaf(x, b.x, fmaf(y, a.w, b.y));
            float m  = fmaxf(1.0f - (fabsf(t0) + fabsf(t1)), 0.0f);
            ac0 = fmaf(b.z, m, ac0);
            ac1 = fmaf(b.w, m, ac1);
            ac2 = fmaf(c,   m, ac2);
        }
    }

    // ---- phase 3: cross-segment reduce + sigmoid + store
    part[seg][lane][0] = ac0;
    part[seg][lane][1] = ac1;
    part[seg][lane][2] = ac2;
    __syncthreads();
    int t = threadIdx.x;
    if (t < 192) {
        const float* pp = &part[0][0][0];        // [seg] stride = 192 floats
        float s = pp[t] + pp[192 + t] + pp[384 + t] + pp[576 + t];
        out[blockIdx.x * 192 + t] = 1.0f / (1.0f + __expf(-4.0f * s));
    }
}

extern "C" void kernel_launch(void* const* d_in, const int* in_sizes, int n_in,
                              void* d_out, int out_size, void* d_ws, size_t ws_size,
                              hipStream_t stream) {
    const float* loc = (const float*)d_in[0];
    const float* mo  = (const float*)d_in[1];
    const float* mso = (const float*)d_in[2];
    const float* col = (const float*)d_in[3];
    const float* alp = (const float*)d_in[4];
    float* out = (float*)d_out;

    float4* A = (float4*)d_ws;                  // (NPTS+1) float4
    float4* B = A + (NPTS + 1);                 // (NPTS+1) float4
    float*  C = (float*)(B + (NPTS + 1));       // (NPTS+1) float

    prep_kernel<<<(NPTS + 255) / 256, 256, 0, stream>>>(loc, mo, mso, col, alp, A, B, C);
    render_kernel<<<(CH * CW) / 64, 256, 0, stream>>>(A, B, C, out);
}

// Round 6
// 15.081 us; speedup vs baseline: 6.3586x; 1.0657x over previous
//
#include <hip/hip_runtime.h>
#include <math.h>

#define NPTS 1024
#define CH 256
#define CW 256
#define NSEG 8          // waves per block = point segments
#define PPS (NPTS/NSEG) // points per segment = 128

// -------- prep: fold all per-point constants into a packed table ------------
// A[n] = (t00, t10, b0, t01)   tij = 0.5*(matrix_offsets + s*I)[i][j]
// B[n] = (t11, b1, ca0, ca1)   b_j = -(ly*t0j + lx*t1j),  ca_c = color_c*alpha
// C[n] = ca2
// Row NPTS is a zero sentinel (contributes 0 regardless of m) used to pad
// survivor lists to a multiple of 4.
__global__ __launch_bounds__(256) void prep_kernel(
    const float* __restrict__ loc, const float* __restrict__ mo,
    const float* __restrict__ mso, const float* __restrict__ col,
    const float* __restrict__ alp,
    float4* __restrict__ A, float4* __restrict__ B, float* __restrict__ C)
{
    int n = blockIdx.x * blockDim.x + threadIdx.x;
    if (n >= NPTS) return;
    float s   = 16.0f * __expf(mso[n]);
    float t00 = 0.5f * (mo[4*n+0] + s);
    float t01 = 0.5f * (mo[4*n+1]);
    float t10 = 0.5f * (mo[4*n+2]);
    float t11 = 0.5f * (mo[4*n+3] + s);
    float ly  = loc[2*n+0];
    float lx  = loc[2*n+1];
    float b0  = -(ly*t00 + lx*t10);
    float b1  = -(ly*t01 + lx*t11);
    float a   = alp[n];
    A[n] = make_float4(t00, t10, b0, t01);
    B[n] = make_float4(t11, b1, col[3*n+0]*a, col[3*n+1]*a);
    C[n] = col[3*n+2]*a;
    if (n == 0) {
        A[NPTS] = make_float4(0.f, 0.f, 0.f, 0.f);
        B[NPTS] = make_float4(0.f, 0.f, 0.f, 0.f);
        C[NPTS] = 0.f;
    }
}

// -------- render: 1024 blocks x 512 threads. 64 px/block (quarter row),
// 8 waves each culling a 128-point segment (ballot compaction), survivors
// evaluated with batched scalar table loads, 8-way LDS reduce + sigmoid. ----
__global__ __launch_bounds__(512) void render_kernel(
    const float4* __restrict__ A, const float4* __restrict__ B,
    const float*  __restrict__ C, float* __restrict__ out)
{
    __shared__ int   list[NSEG][132];
    __shared__ float part[NSEG][64][3];

    int lane = threadIdx.x & 63;
    int seg  = threadIdx.x >> 6;
    int h    = blockIdx.x >> 2;
    int w0   = (blockIdx.x & 3) << 6;

    float y  = fmaf((float)h,           2.0f/255.0f, -1.0f);
    float x  = fmaf((float)(w0 + lane), 2.0f/255.0f, -1.0f);
    float x0 = fmaf((float)w0,          2.0f/255.0f, -1.0f);
    float x1 = fmaf((float)(w0 + 63),   2.0f/255.0f, -1.0f);

    // ---- phase 1: conservative cull of this wave's 128 points vs the 64-px
    // interval. t0(x), t1(x) linear in x at fixed y; interval min of |t| is 0
    // on sign change, else min endpoint magnitude. Skip iff min|t0|+min|t1|>=1
    // (m <= 0 over the whole tile) — conservative => identical output.
    int segbase = seg << 7;
    unsigned long long lt = (1ull << lane) - 1ull;
    int base = 0;
    #pragma unroll
    for (int j = 0; j < 2; ++j) {
        int idx = segbase + (j << 6) + lane;
        float4 a = A[idx];
        float4 b = B[idx];
        float c0 = fmaf(y, a.x, a.z);
        float c1 = fmaf(y, a.w, b.y);
        float g00 = fmaf(x0, a.y, c0), g01 = fmaf(x1, a.y, c0);
        float g10 = fmaf(x0, b.x, c1), g11 = fmaf(x1, b.x, c1);
        float m0 = (g00 * g01 <= 0.0f) ? 0.0f : fminf(fabsf(g00), fabsf(g01));
        float m1 = (g10 * g11 <= 0.0f) ? 0.0f : fminf(fabsf(g10), fabsf(g11));
        bool keep = (m0 + m1) < 1.0f;
        unsigned long long mk = __ballot(keep);
        if (keep) list[seg][base + __popcll(mk & lt)] = idx;
        base += __popcll(mk);
    }
    int cnt  = base;
    int cntp = (cnt + 3) & ~3;
    if (lane < cntp - cnt) list[seg][cnt + lane] = NPTS;   // sentinel pad

    // ---- phase 2: evaluate survivors; batch the 4 indices + 12 scalar loads
    // per group so the s_loads overlap, then 4x compute.
    float ac0 = 0.f, ac1 = 0.f, ac2 = 0.f;
    for (int i = 0; i < cntp; i += 4) {
        int4 iv = *(const int4*)&list[seg][i];   // wave-uniform LDS read
        int i0 = __builtin_amdgcn_readfirstlane(iv.x);
        int i1 = __builtin_amdgcn_readfirstlane(iv.y);
        int i2 = __builtin_amdgcn_readfirstlane(iv.z);
        int i3 = __builtin_amdgcn_readfirstlane(iv.w);
        float4 a0 = A[i0], b0 = B[i0];
        float4 a1 = A[i1], b1 = B[i1];
        float4 a2 = A[i2], b2 = B[i2];
        float4 a3 = A[i3], b3 = B[i3];
        float  c0 = C[i0], c1 = C[i1], c2 = C[i2], c3 = C[i3];
        {
            float t0 = fmaf(x, a0.y, fmaf(y, a0.x, a0.z));
            float t1 = fmaf(x, b0.x, fmaf(y, a0.w, b0.y));
            float m  = fmaxf(1.0f - (fabsf(t0) + fabsf(t1)), 0.0f);
            ac0 = fmaf(b0.z, m, ac0); ac1 = fmaf(b0.w, m, ac1); ac2 = fmaf(c0, m, ac2);
        }
        {
            float t0 = fmaf(x, a1.y, fmaf(y, a1.x, a1.z));
            float t1 = fmaf(x, b1.x, fmaf(y, a1.w, b1.y));
            float m  = fmaxf(1.0f - (fabsf(t0) + fabsf(t1)), 0.0f);
            ac0 = fmaf(b1.z, m, ac0); ac1 = fmaf(b1.w, m, ac1); ac2 = fmaf(c1, m, ac2);
        }
        {
            float t0 = fmaf(x, a2.y, fmaf(y, a2.x, a2.z));
            float t1 = fmaf(x, b2.x, fmaf(y, a2.w, b2.y));
            float m  = fmaxf(1.0f - (fabsf(t0) + fabsf(t1)), 0.0f);
            ac0 = fmaf(b2.z, m, ac0); ac1 = fmaf(b2.w, m, ac1); ac2 = fmaf(c2, m, ac2);
        }
        {
            float t0 = fmaf(x, a3.y, fmaf(y, a3.x, a3.z));
            float t1 = fmaf(x, b3.x, fmaf(y, a3.w, b3.y));
            float m  = fmaxf(1.0f - (fabsf(t0) + fabsf(t1)), 0.0f);
            ac0 = fmaf(b3.z, m, ac0); ac1 = fmaf(b3.w, m, ac1); ac2 = fmaf(c3, m, ac2);
        }
    }

    // ---- phase 3: cross-segment reduce + sigmoid + store
    part[seg][lane][0] = ac0;
    part[seg][lane][1] = ac1;
    part[seg][lane][2] = ac2;
    __syncthreads();
    int t = threadIdx.x;
    if (t < 192) {
        const float* pp = &part[0][0][0];        // [seg] stride = 192 floats
        float s = 0.f;
        #pragma unroll
        for (int k = 0; k < NSEG; ++k) s += pp[k * 192 + t];
        out[blockIdx.x * 192 + t] = 1.0f / (1.0f + __expf(-4.0f * s));
    }
}

extern "C" void kernel_launch(void* const* d_in, const int* in_sizes, int n_in,
                              void* d_out, int out_size, void* d_ws, size_t ws_size,
                              hipStream_t stream) {
    const float* loc = (const float*)d_in[0];
    const float* mo  = (const float*)d_in[1];
    const float* mso = (const float*)d_in[2];
    const float* col = (const float*)d_in[3];
    const float* alp = (const float*)d_in[4];
    float* out = (float*)d_out;

    float4* A = (float4*)d_ws;                  // (NPTS+1) float4
    float4* B = A + (NPTS + 1);                 // (NPTS+1) float4
    float*  C = (float*)(B + (NPTS + 1));       // (NPTS+1) float

    prep_kernel<<<(NPTS + 255) / 256, 256, 0, stream>>>(loc, mo, mso, col, alp, A, B, C);
    render_kernel<<<(CH * CW) / 64, 512, 0, stream>>>(A, B, C, out);
}

// Round 7
// 10.609 us; speedup vs baseline: 9.0391x; 1.4216x over previous
//
#include <hip/hip_runtime.h>
#include <math.h>

#define NPTS 1024
#define CH 256
#define CW 256
#define NSEG 8     // waves per block = point segments (128 pts each)
#define CAP  68    // survivor-record slots per wave (drain threshold 64 + pad)

// Single fused kernel. 1024 blocks x 512 threads; block owns 64 consecutive
// pixels of one row (y uniform). Each of the 8 waves:
//   phase 1: for its 128 points (2 rounds of 64), folds the per-point
//     constants (scale/exp, 0.5*, bias, color*alpha) in registers, runs the
//     exact-conservative interval cull (t0,t1 linear in x at fixed y; interval
//     min |t| = 0 on sign change else min endpoint magnitude; skip iff
//     min|t0|+min|t1| >= 1), and ballot-compacts SURVIVOR RECORDS into LDS.
//     Capacity-68 list with wave-uniform drain keeps worst case correct;
//     pad records are all-zero (ca=0 => contribution exactly 0).
//   phase 2: evaluates records at wave-uniform LDS addresses (broadcast
//     ds_read_b128, conflict-free), groups of 4 for ILP.
//   phase 3: 8-way LDS reduce + sigmoid + coalesced store.
__global__ __launch_bounds__(512) void fused_kernel(
    const float* __restrict__ loc,   // (N,2) [y,x]
    const float* __restrict__ mo,    // (N,2,2)
    const float* __restrict__ mso,   // (N,)
    const float* __restrict__ col,   // (N,3)
    const float* __restrict__ alp,   // (N,)
    float* __restrict__ out)
{
    __shared__ float4 recA[NSEG][CAP];     // t00, t10, b0, t01
    __shared__ float4 recB[NSEG][CAP];     // t11, b1, ca0, ca1
    __shared__ float  recC[NSEG][CAP];     // ca2
    __shared__ float  part[NSEG][64][3];

    int lane = threadIdx.x & 63;
    int seg  = threadIdx.x >> 6;
    int h    = blockIdx.x >> 2;
    int w0   = (blockIdx.x & 3) << 6;

    float y  = fmaf((float)h,           2.0f/255.0f, -1.0f);
    float x  = fmaf((float)(w0 + lane), 2.0f/255.0f, -1.0f);
    float x0 = fmaf((float)w0,          2.0f/255.0f, -1.0f);
    float x1 = fmaf((float)(w0 + 63),   2.0f/255.0f, -1.0f);

    unsigned long long lt = (1ull << lane) - 1ull;
    int base = 0;
    float ac0 = 0.f, ac1 = 0.f, ac2 = 0.f;

    auto evalList = [&](int cntp) {
        for (int i = 0; i < cntp; i += 4) {
            #pragma unroll
            for (int j = 0; j < 4; ++j) {
                float4 a = recA[seg][i + j];   // uniform addr -> broadcast
                float4 b = recB[seg][i + j];
                float  c = recC[seg][i + j];
                float t0 = fmaf(x, a.y, fmaf(y, a.x, a.z));
                float t1 = fmaf(x, b.x, fmaf(y, a.w, b.y));
                float m  = fmaxf(1.0f - (fabsf(t0) + fabsf(t1)), 0.0f);
                ac0 = fmaf(b.z, m, ac0);
                ac1 = fmaf(b.w, m, ac1);
                ac2 = fmaf(c,   m, ac2);
            }
        }
    };

    int segbase = seg << 7;
    #pragma unroll
    for (int r = 0; r < 2; ++r) {
        int n = segbase + (r << 6) + lane;
        // ---- fused prep (registers only) ----
        float2 l  = ((const float2*)loc)[n];
        float4 m4 = ((const float4*)mo)[n];       // T00,T01,T10,T11
        float  s  = 16.0f * __expf(mso[n]);       // sqrt(1024)/2 * exp(off)
        float  al = alp[n];
        float t00 = 0.5f * (m4.x + s);
        float t01 = 0.5f *  m4.y;
        float t10 = 0.5f *  m4.z;
        float t11 = 0.5f * (m4.w + s);
        float b0  = -(l.x * t00 + l.y * t10);
        float b1  = -(l.x * t01 + l.y * t11);
        // ---- conservative cull over [x0,x1] at fixed y ----
        float c0  = fmaf(y, t00, b0);
        float c1  = fmaf(y, t01, b1);
        float g00 = fmaf(x0, t10, c0), g01 = fmaf(x1, t10, c0);
        float g10 = fmaf(x0, t11, c1), g11 = fmaf(x1, t11, c1);
        float m0 = (g00 * g01 <= 0.0f) ? 0.0f : fminf(fabsf(g00), fabsf(g01));
        float m1 = (g10 * g11 <= 0.0f) ? 0.0f : fminf(fabsf(g10), fabsf(g11));
        bool keep = (m0 + m1) < 1.0f;
        unsigned long long mk = __ballot(keep);
        int cr = __popcll(mk);

        if (base + cr > 64) {                     // wave-uniform drain
            int cntp = (base + 3) & ~3;
            if (lane < cntp - base) {
                recA[seg][base + lane] = make_float4(0.f, 0.f, 0.f, 0.f);
                recB[seg][base + lane] = make_float4(0.f, 0.f, 0.f, 0.f);
                recC[seg][base + lane] = 0.f;
            }
            evalList(cntp);
            base = 0;
        }
        if (keep) {
            int slot = base + __popcll(mk & lt);
            recA[seg][slot] = make_float4(t00, t10, b0, t01);
            recB[seg][slot] = make_float4(t11, b1, col[3*n+0] * al, col[3*n+1] * al);
            recC[seg][slot] = col[3*n+2] * al;
        }
        base += cr;
    }
    {   // final drain
        int cntp = (base + 3) & ~3;
        if (lane < cntp - base) {
            recA[seg][base + lane] = make_float4(0.f, 0.f, 0.f, 0.f);
            recB[seg][base + lane] = make_float4(0.f, 0.f, 0.f, 0.f);
            recC[seg][base + lane] = 0.f;
        }
        evalList(cntp);
    }

    // ---- phase 3: cross-segment reduce + sigmoid + store ----
    part[seg][lane][0] = ac0;
    part[seg][lane][1] = ac1;
    part[seg][lane][2] = ac2;
    __syncthreads();
    int t = threadIdx.x;
    if (t < 192) {
        const float* pp = &part[0][0][0];         // [seg] stride = 192 floats
        float sum = 0.f;
        #pragma unroll
        for (int k = 0; k < NSEG; ++k) sum += pp[k * 192 + t];
        out[blockIdx.x * 192 + t] = 1.0f / (1.0f + __expf(-4.0f * sum));
    }
}

extern "C" void kernel_launch(void* const* d_in, const int* in_sizes, int n_in,
                              void* d_out, int out_size, void* d_ws, size_t ws_size,
                              hipStream_t stream) {
    const float* loc = (const float*)d_in[0];
    const float* mo  = (const float*)d_in[1];
    const float* mso = (const float*)d_in[2];
    const float* col = (const float*)d_in[3];
    const float* alp = (const float*)d_in[4];
    float* out = (float*)d_out;
    (void)d_ws; (void)ws_size;

    fused_kernel<<<(CH * CW) / 64, 512, 0, stream>>>(loc, mo, mso, col, alp, out);
}